// Round 1
// baseline (6027.777 us; speedup 1.0000x reference)
//
#include <hip/hip_runtime.h>

#define B_SZ   32
#define T_LEN  160000
#define NFFT   1024
#define HOP    320
#define FRAMES 501
#define NROWS  1026
#define NBINS  513
#define PAD    512

#define TM  128          // bins per block tile
#define TN  32           // frames per block tile
#define KT  32           // k-chunk
#define TMP 132          // padded LDS row stride for basis tile (16B-aligned rows)
#define XU_LEN ((TN - 1) * HOP + NFFT)   // 10944 floats

__launch_bounds__(256, 2)
__global__ void stft_fp32_kernel(const float* __restrict__ x,
                                 const float* __restrict__ basis,
                                 float* __restrict__ out) {
    __shared__ float xu[XU_LEN];       // 43776 B
    __shared__ float bs[KT * TMP];     // 16896 B

    const int tid = threadIdx.x;
    const int tx  = tid & 31;          // m-direction (32 threads x 4 bins = 128)
    const int ty  = tid >> 5;          // f-direction (8 threads x 4 frames = 32)
    const int b   = blockIdx.z;
    const int fg0 = blockIdx.x * TN;   // first frame of tile
    const int mg0 = blockIdx.y * TM;   // first basis row of tile

    const float* xb = x + (size_t)b * T_LEN;

    // ---- stage x-union for this frame tile (once) ----
    // xp index of union start = fg0*HOP ; x index = that - PAD
    const int xbase = fg0 * HOP - PAD;
    for (int i = tid; i < XU_LEN / 4; i += 256) {
        const int xi = xbase + i * 4;
        float4 v;
        if (xi >= 0 && xi + 3 < T_LEN) {
            v = *(const float4*)(xb + xi);
        } else {
            v.x = (xi + 0 >= 0 && xi + 0 < T_LEN) ? xb[xi + 0] : 0.f;
            v.y = (xi + 1 >= 0 && xi + 1 < T_LEN) ? xb[xi + 1] : 0.f;
            v.z = (xi + 2 >= 0 && xi + 2 < T_LEN) ? xb[xi + 2] : 0.f;
            v.w = (xi + 3 >= 0 && xi + 3 < T_LEN) ? xb[xi + 3] : 0.f;
        }
        *(float4*)(xu + i * 4) = v;
    }

    float acc[4][4] = {};
    const int m0 = tx * 4;

    for (int k0 = 0; k0 < NFFT; k0 += KT) {
        __syncthreads();   // previous chunk's bs reads done (also covers xu staging)

        // ---- stage basis chunk, transposed: bs[kk][m] = basis[mg0+m][k0+kk] ----
        #pragma unroll
        for (int p = 0; p < 4; ++p) {
            const int idx = p * 256 + tid;     // 0..1023
            const int m   = idx >> 3;          // 0..127
            const int cg  = idx & 7;           // 0..7 (float4 column group)
            const int row = mg0 + m;
            float4 v = make_float4(0.f, 0.f, 0.f, 0.f);
            if (row < NROWS)
                v = *(const float4*)(basis + (size_t)row * NFFT + k0 + cg * 4);
            const int kk = cg * 4;
            bs[(kk + 0) * TMP + m] = v.x;
            bs[(kk + 1) * TMP + m] = v.y;
            bs[(kk + 2) * TMP + m] = v.z;
            bs[(kk + 3) * TMP + m] = v.w;
        }
        __syncthreads();

        // ---- compute: 4x4 register tile, 4 k's per iteration ----
        #pragma unroll
        for (int kk = 0; kk < KT; kk += 4) {
            float4 bv[4];
            #pragma unroll
            for (int i = 0; i < 4; ++i)
                bv[i] = *(const float4*)(bs + (kk + i) * TMP + m0);
            float4 xv[4];
            #pragma unroll
            for (int j = 0; j < 4; ++j)
                xv[j] = *(const float4*)(xu + (ty * 4 + j) * HOP + k0 + kk);
            #pragma unroll
            for (int j = 0; j < 4; ++j) {
                const float xj0 = xv[j].x, xj1 = xv[j].y, xj2 = xv[j].z, xj3 = xv[j].w;
                acc[0][j] += bv[0].x * xj0 + bv[1].x * xj1 + bv[2].x * xj2 + bv[3].x * xj3;
                acc[1][j] += bv[0].y * xj0 + bv[1].y * xj1 + bv[2].y * xj2 + bv[3].y * xj3;
                acc[2][j] += bv[0].z * xj0 + bv[1].z * xj1 + bv[2].z * xj2 + bv[3].z * xj3;
                acc[3][j] += bv[0].w * xj0 + bv[1].w * xj1 + bv[2].w * xj2 + bv[3].w * xj3;
            }
        }
    }

    // ---- epilogue: out[b][bin][f][c], c=0 cos rows (k<513), c=1 sin rows ----
    #pragma unroll
    for (int mi = 0; mi < 4; ++mi) {
        const int row = mg0 + m0 + mi;
        if (row >= NROWS) continue;
        const int bin = (row < NBINS) ? row : row - NBINS;
        const int c   = (row < NBINS) ? 0 : 1;
        const size_t obase = (((size_t)b * NBINS + bin) * FRAMES) * 2 + c;
        #pragma unroll
        for (int fj = 0; fj < 4; ++fj) {
            const int f = fg0 + ty * 4 + fj;
            if (f < FRAMES) out[obase + (size_t)f * 2] = acc[mi][fj];
        }
    }
}

extern "C" void kernel_launch(void* const* d_in, const int* in_sizes, int n_in,
                              void* d_out, int out_size, void* d_ws, size_t ws_size,
                              hipStream_t stream) {
    const float* x     = (const float*)d_in[0];
    const float* basis = (const float*)d_in[1];
    float* out         = (float*)d_out;

    dim3 grid((FRAMES + TN - 1) / TN,   // 16 frame tiles
              (NROWS + TM - 1) / TM,    // 9 row tiles
              B_SZ);                    // 32 batches
    stft_fp32_kernel<<<grid, dim3(256), 0, stream>>>(x, basis, out);
}

// Round 2
// 144.271 us; speedup vs baseline: 41.7808x; 41.7808x over previous
//
#include <hip/hip_runtime.h>

#define B_SZ   32
#define T_LEN  160000
#define NFFT   1024
#define HOP    320
#define FRAMES 501
#define NROWS  1026
#define NBINS  513
#define PADL   512

#define MROWS_PAD 1152
#define XP_STRIDE 164864                  // padded per-batch xp length (elements, = 161*1024)
#define WS_XP_OFF (MROWS_PAD * NFFT)      // ushort elements offset of xp region

typedef __bf16 bf16x8  __attribute__((ext_vector_type(8)));
typedef float  floatx4 __attribute__((ext_vector_type(4)));

__device__ __forceinline__ unsigned short f2bf(float f) {
    unsigned u = __builtin_bit_cast(unsigned, f);
    u += 0x7FFFu + ((u >> 16) & 1u);      // round-to-nearest-even
    return (unsigned short)(u >> 16);
}

// basis fp32 [1026][1024] -> ws bf16 [1152][1024], rows interleaved: dst row 2j=cos_j, 2j+1=sin_j
__global__ void conv_basis(const float* __restrict__ basis, unsigned short* __restrict__ dst) {
    const int gid = blockIdx.x * 256 + threadIdx.x;   // 4 elems per thread
    const int i4  = gid * 4;
    const int row = i4 >> 10;
    const int col = i4 & 1023;
    ushort4 o = {0, 0, 0, 0};
    if (row < NROWS) {
        const int j = row >> 1, c = row & 1;
        const float4 v = *(const float4*)(basis + (size_t)(j + c * NBINS) * NFFT + col);
        o.x = f2bf(v.x); o.y = f2bf(v.y); o.z = f2bf(v.z); o.w = f2bf(v.w);
    }
    *(ushort4*)(dst + i4) = o;
}

// x fp32 [32][160000] -> ws bf16 padded signal per batch: [512 zeros][x][zeros to XP_STRIDE]
__global__ void conv_xp(const float* __restrict__ x, unsigned short* __restrict__ dst) {
    const int b   = blockIdx.y;
    const int pos = (blockIdx.x * 256 + threadIdx.x) * 4;   // 4-elem groups never straddle bounds
    ushort4 o = {0, 0, 0, 0};
    if (pos >= PADL && pos < T_LEN + PADL) {
        const float4 v = *(const float4*)(x + (size_t)b * T_LEN + (pos - PADL));
        o.x = f2bf(v.x); o.y = f2bf(v.y); o.z = f2bf(v.z); o.w = f2bf(v.w);
    }
    *(ushort4*)(dst + (size_t)b * XP_STRIDE + pos) = o;
}

__device__ __forceinline__ void gl_lds16(const void* g, void* l) {
    __builtin_amdgcn_global_load_lds(
        (const __attribute__((address_space(1))) unsigned int*)g,
        (__attribute__((address_space(3))) unsigned int*)l, 16, 0, 0);
}

// C[m=interleaved basis row][n=frame] = sum_k basis_bf[m][k] * xp_bf[n*HOP + k]
__launch_bounds__(256)
__global__ void stft_mfma_kernel(const unsigned short* __restrict__ basisb,
                                 const unsigned short* __restrict__ xpb,
                                 float* __restrict__ out) {
    __shared__ unsigned short lsA[128 * 32];   // [m][k] rows of 64 B
    __shared__ unsigned short lsB[128 * 32];   // [f][k] rows of 64 B

    const int tid  = threadIdx.x;
    const int lane = tid & 63;
    const int w    = tid >> 6;        // wave 0..3
    const int wm   = w & 1;           // m-half of 128x128 tile
    const int wn   = w >> 1;          // n-half
    const int r0   = lane & 15;
    const int quad = lane >> 4;

    const int fg0 = blockIdx.x * 128;           // frame tile base (0,128,256,384)
    const int mg0 = blockIdx.y * 128;           // row tile base (0..1024)
    const int b   = blockIdx.z;

    const unsigned short* xpbb = xpb + (size_t)b * XP_STRIDE;

    // staging indices (2 issues per thread per matrix per chunk)
    const int idx0 = tid;           // 0..255
    const int idx1 = 256 + tid;     // 256..511

    floatx4 acc[4][4] = {};

    for (int k0 = 0; k0 < NFFT; k0 += 32) {
        __syncthreads();   // previous chunk's fragment reads complete

        // ---- stage A (basis rows) and B (framed signal) via async LDS DMA ----
        #pragma unroll
        for (int i = 0; i < 2; ++i) {
            const int idx = (i == 0) ? idx0 : idx1;  // 0..511
            const int mm  = idx >> 2;                // 0..127
            const int ko  = (idx & 3) * 8;           // 0,8,16,24
            gl_lds16(basisb + (((size_t)(mg0 + mm)) << 10) + k0 + ko, &lsA[idx * 8]);
            gl_lds16(xpbb + (size_t)(fg0 + mm) * HOP + k0 + ko,       &lsB[idx * 8]);
        }
        __syncthreads();   // compiler drains vmcnt(0) before barrier

        // ---- fragments + 16 MFMAs per wave ----
        bf16x8 af[4], bf[4];
        #pragma unroll
        for (int mt = 0; mt < 4; ++mt)
            af[mt] = *(const bf16x8*)(&lsA[(wm * 64 + mt * 16 + r0) * 32 + quad * 8]);
        #pragma unroll
        for (int nt = 0; nt < 4; ++nt)
            bf[nt] = *(const bf16x8*)(&lsB[(wn * 64 + nt * 16 + r0) * 32 + quad * 8]);

        #pragma unroll
        for (int mt = 0; mt < 4; ++mt)
            #pragma unroll
            for (int nt = 0; nt < 4; ++nt)
                acc[mt][nt] = __builtin_amdgcn_mfma_f32_16x16x32_bf16(
                    af[mt], bf[nt], acc[mt][nt], 0, 0, 0);
    }

    // ---- epilogue: D rows are interleaved (cos,sin) pairs -> coalesced float2 stores ----
    const int mbase = mg0 + wm * 64 + quad * 4;   // even
    const int fbase = fg0 + wn * 64 + r0;
    #pragma unroll
    for (int nt = 0; nt < 4; ++nt) {
        const int f = fbase + nt * 16;
        if (f >= FRAMES) continue;
        #pragma unroll
        for (int mt = 0; mt < 4; ++mt) {
            const int mrow = mbase + mt * 16;
            const floatx4 v = acc[mt][nt];
            #pragma unroll
            for (int p = 0; p < 2; ++p) {
                const int row = mrow + 2 * p;
                if (row < NROWS) {
                    const int bin = row >> 1;
                    float2 val;
                    val.x = v[2 * p];      // cos
                    val.y = v[2 * p + 1];  // sin
                    *(float2*)(out + (((size_t)b * NBINS + bin) * FRAMES + f) * 2) = val;
                }
            }
        }
    }
}

extern "C" void kernel_launch(void* const* d_in, const int* in_sizes, int n_in,
                              void* d_out, int out_size, void* d_ws, size_t ws_size,
                              hipStream_t stream) {
    const float* x     = (const float*)d_in[0];
    const float* basis = (const float*)d_in[1];
    float* out         = (float*)d_out;

    unsigned short* basis_bf = (unsigned short*)d_ws;
    unsigned short* xp_bf    = (unsigned short*)d_ws + WS_XP_OFF;

    conv_basis<<<dim3(MROWS_PAD * NFFT / 1024), dim3(256), 0, stream>>>(basis, basis_bf);
    conv_xp<<<dim3(XP_STRIDE / 1024, B_SZ), dim3(256), 0, stream>>>(x, xp_bf);

    dim3 grid(4, 9, B_SZ);   // 4 frame-tiles x 9 row-tiles x 32 batches = 1152 blocks
    stft_mfma_kernel<<<grid, dim3(256), 0, stream>>>(basis_bf, xp_bf, out);
}

// Round 3
// 131.542 us; speedup vs baseline: 45.8239x; 1.0968x over previous
//
#include <hip/hip_runtime.h>

#define B_SZ   32
#define T_LEN  160000
#define NFFT   1024
#define HOP    320
#define FRAMES 501
#define NBINS  513
#define PADL   512

#define MROWS_BF  1024                    // interleaved cos/sin rows staged as bf16 (bins 0..511)
#define XP_STRIDE 164864                  // padded per-batch xp length (elements)
#define WS_XP_OFF (MROWS_BF * NFFT)       // ushort-element offset of xp region in ws
#define XP_CHUNKS (XP_STRIDE / 8)         // 20608 8-elem chunks per batch

typedef __bf16 bf16x8  __attribute__((ext_vector_type(8)));
typedef float  floatx4 __attribute__((ext_vector_type(4)));

__device__ __forceinline__ unsigned short f2bf(float f) {
    unsigned u = __builtin_bit_cast(unsigned, f);
    u += 0x7FFFu + ((u >> 16) & 1u);      // round-to-nearest-even
    return (unsigned short)(u >> 16);
}
__device__ __forceinline__ float bf2f(unsigned short u) {
    return __builtin_bit_cast(float, (unsigned)u << 16);
}

// basis fp32 [1026][1024] -> ws bf16 [1024][1024], dst row 2j=cos_j, 2j+1=sin_j (j<512)
__global__ void conv_basis(const float* __restrict__ basis, unsigned short* __restrict__ dst) {
    const int gid = blockIdx.x * 256 + threadIdx.x;   // 8 elems per thread
    const int row = gid >> 7;                         // 0..1023
    const int col = (gid & 127) * 8;
    const int j = row >> 1, c = row & 1;
    const float* src = basis + (size_t)(j + c * NBINS) * NFFT + col;
    const float4 v0 = *(const float4*)(src);
    const float4 v1 = *(const float4*)(src + 4);
    ushort4 o0, o1;
    o0.x = f2bf(v0.x); o0.y = f2bf(v0.y); o0.z = f2bf(v0.z); o0.w = f2bf(v0.w);
    o1.x = f2bf(v1.x); o1.y = f2bf(v1.y); o1.z = f2bf(v1.z); o1.w = f2bf(v1.w);
    *(ushort4*)(dst + (size_t)gid * 8)     = o0;
    *(ushort4*)(dst + (size_t)gid * 8 + 4) = o1;
}

// x fp32 [32][160000] -> ws bf16 padded signal per batch: [512 zeros][x][zeros to XP_STRIDE]
__global__ void conv_xp(const float* __restrict__ x, unsigned short* __restrict__ dst) {
    const int gid = blockIdx.x * 256 + threadIdx.x;   // 8 elems per thread
    const int b   = gid / XP_CHUNKS;
    const int pos = (gid - b * XP_CHUNKS) * 8;        // [512,160512) never straddled (both %8==0)
    ushort4 o0 = {0,0,0,0}, o1 = {0,0,0,0};
    if (pos >= PADL && pos < T_LEN + PADL) {
        const float* src = x + (size_t)b * T_LEN + (pos - PADL);
        const float4 v0 = *(const float4*)(src);
        const float4 v1 = *(const float4*)(src + 4);
        o0.x = f2bf(v0.x); o0.y = f2bf(v0.y); o0.z = f2bf(v0.z); o0.w = f2bf(v0.w);
        o1.x = f2bf(v1.x); o1.y = f2bf(v1.y); o1.z = f2bf(v1.z); o1.w = f2bf(v1.w);
    }
    unsigned short* d = dst + (size_t)b * XP_STRIDE + pos;
    *(ushort4*)(d)     = o0;
    *(ushort4*)(d + 4) = o1;
}

// bin 512: real = cos_512 . frame (fp32 basis x bf16 xp), imag = 0 (exact at f64 precision)
__global__ void bin512_kernel(const float* __restrict__ basis,
                              const unsigned short* __restrict__ xpb,
                              float* __restrict__ out) {
    const int lane = threadIdx.x & 63;
    const int w    = threadIdx.x >> 6;
    const int f    = blockIdx.x * 4 + w;
    const int b    = blockIdx.y;
    if (f >= FRAMES) return;                          // wave-uniform
    const unsigned short* xf = xpb + (size_t)b * XP_STRIDE + f * HOP + lane * 16;
    const float* br = basis + (size_t)512 * NFFT + lane * 16;
    float sum = 0.f;
    #pragma unroll
    for (int c = 0; c < 4; ++c) {
        const ushort4 u = *(const ushort4*)(xf + c * 4);
        const float4  v = *(const float4*)(br + c * 4);
        sum += v.x * bf2f(u.x) + v.y * bf2f(u.y) + v.z * bf2f(u.z) + v.w * bf2f(u.w);
    }
    #pragma unroll
    for (int off = 32; off >= 1; off >>= 1) sum += __shfl_down(sum, off);
    if (lane == 0) {
        float2 val; val.x = sum; val.y = 0.f;
        *(float2*)(out + (((size_t)b * NBINS + 512) * FRAMES + f) * 2) = val;
    }
}

__device__ __forceinline__ void gl_lds16(const void* g, void* l) {
    __builtin_amdgcn_global_load_lds(
        (const __attribute__((address_space(1))) unsigned int*)g,
        (__attribute__((address_space(3))) unsigned int*)l, 16, 0, 0);
}

// C[m=interleaved basis row][n=frame] = sum_k basis_bf[m][k] * xp_bf[n*HOP + k]
__launch_bounds__(256, 4)
__global__ void stft_mfma_kernel(const unsigned short* __restrict__ basisb,
                                 const unsigned short* __restrict__ xpb,
                                 float* __restrict__ out) {
    // two BK=32 panels per matrix: 64 B rows keep DMA wave-uniform and banks balanced
    __shared__ unsigned short lsA[2][128 * 32];
    __shared__ unsigned short lsB[2][128 * 32];

    const int tid  = threadIdx.x;
    const int lane = tid & 63;
    const int w    = tid >> 6;        // wave 0..3
    const int wm   = w & 1;           // m-half of 128x128 tile
    const int wn   = w >> 1;          // n-half
    const int r0   = lane & 15;
    const int quad = lane >> 4;

    const int fg0 = blockIdx.x * 128;           // frame tile base (0,128,256,384)
    const int mg0 = blockIdx.y * 128;           // row tile base (0..896)
    const int b   = blockIdx.z;

    const unsigned short* xpbb = xpb + (size_t)b * XP_STRIDE;

    floatx4 acc[4][4] = {};

    for (int k0 = 0; k0 < NFFT; k0 += 64) {
        __syncthreads();   // previous chunk's fragment reads complete

        #pragma unroll
        for (int h = 0; h < 2; ++h) {
            #pragma unroll
            for (int i = 0; i < 2; ++i) {
                const int idx = i * 256 + tid;       // 0..511
                const int mm  = idx >> 2;            // 0..127
                const int ko  = (idx & 3) * 8;       // 0,8,16,24
                gl_lds16(basisb + (((size_t)(mg0 + mm)) << 10) + k0 + h * 32 + ko,
                         &lsA[h][idx * 8]);
                gl_lds16(xpbb + (size_t)(fg0 + mm) * HOP + k0 + h * 32 + ko,
                         &lsB[h][idx * 8]);
            }
        }
        __syncthreads();   // vmcnt(0) drain

        #pragma unroll
        for (int h = 0; h < 2; ++h) {
            bf16x8 af[4], bf[4];
            #pragma unroll
            for (int mt = 0; mt < 4; ++mt)
                af[mt] = *(const bf16x8*)(&lsA[h][(wm * 64 + mt * 16 + r0) * 32 + quad * 8]);
            #pragma unroll
            for (int nt = 0; nt < 4; ++nt)
                bf[nt] = *(const bf16x8*)(&lsB[h][(wn * 64 + nt * 16 + r0) * 32 + quad * 8]);

            #pragma unroll
            for (int mt = 0; mt < 4; ++mt)
                #pragma unroll
                for (int nt = 0; nt < 4; ++nt)
                    acc[mt][nt] = __builtin_amdgcn_mfma_f32_16x16x32_bf16(
                        af[mt], bf[nt], acc[mt][nt], 0, 0, 0);
        }
    }

    // epilogue: rows are interleaved (cos,sin) pairs -> coalesced float2 stores, all rows valid
    const int mbase = mg0 + wm * 64 + quad * 4;   // even
    const int fbase = fg0 + wn * 64 + r0;
    #pragma unroll
    for (int nt = 0; nt < 4; ++nt) {
        const int f = fbase + nt * 16;
        if (f >= FRAMES) continue;
        #pragma unroll
        for (int mt = 0; mt < 4; ++mt) {
            const int mrow = mbase + mt * 16;
            const floatx4 v = acc[mt][nt];
            #pragma unroll
            for (int p = 0; p < 2; ++p) {
                const int bin = (mrow + 2 * p) >> 1;
                float2 val;
                val.x = v[2 * p];      // cos
                val.y = v[2 * p + 1];  // sin
                *(float2*)(out + (((size_t)b * NBINS + bin) * FRAMES + f) * 2) = val;
            }
        }
    }
}

extern "C" void kernel_launch(void* const* d_in, const int* in_sizes, int n_in,
                              void* d_out, int out_size, void* d_ws, size_t ws_size,
                              hipStream_t stream) {
    const float* x     = (const float*)d_in[0];
    const float* basis = (const float*)d_in[1];
    float* out         = (float*)d_out;

    unsigned short* basis_bf = (unsigned short*)d_ws;
    unsigned short* xp_bf    = (unsigned short*)d_ws + WS_XP_OFF;

    conv_basis<<<dim3(MROWS_BF * NFFT / (8 * 256)), dim3(256), 0, stream>>>(basis, basis_bf);
    conv_xp<<<dim3(B_SZ * XP_CHUNKS / 256), dim3(256), 0, stream>>>(x, xp_bf);
    bin512_kernel<<<dim3((FRAMES + 3) / 4, B_SZ), dim3(256), 0, stream>>>(basis, xp_bf, out);

    dim3 grid(4, 8, B_SZ);   // 4 frame-tiles x 8 row-tiles x 32 batches = 1024 blocks
    stft_mfma_kernel<<<grid, dim3(256), 0, stream>>>(basis_bf, xp_bf, out);
}